// Round 16
// baseline (155.941 us; speedup 1.0000x reference)
//
#include <hip/hip_runtime.h>
#include <math.h>

#define H 128
#define LN_EPS 1e-5f

typedef __attribute__((ext_vector_type(8))) short  bf16x8;
typedef __attribute__((ext_vector_type(4))) float  f32x4;
typedef __attribute__((ext_vector_type(2))) float  f32x2;
typedef __attribute__((ext_vector_type(8))) unsigned short ushort8v;
typedef __attribute__((ext_vector_type(4))) unsigned int uint4v;

__device__ __forceinline__ int imin(int a, int b) { return a < b ? a : b; }
__device__ __forceinline__ int clampi(int v, int lo, int hi) { return v < lo ? lo : (v > hi ? hi : v); }
__device__ __forceinline__ unsigned short f2bf(float f) {
    unsigned u = __float_as_uint(f);
    unsigned r = (u + 0x7fffu + ((u >> 16) & 1u)) >> 16;   // RNE
    return (unsigned short)r;
}
__device__ __forceinline__ float bf2f(unsigned short u) {
    return __uint_as_float(((unsigned)u) << 16);
}

// packed dual-f32 ops (VOP3P) — hipcc does not auto-emit these
__device__ __forceinline__ f32x2 pk_add(f32x2 a, f32x2 b) {
    f32x2 d; asm("v_pk_add_f32 %0, %1, %2" : "=v"(d) : "v"(a), "v"(b)); return d;
}
__device__ __forceinline__ f32x2 pk_fma(f32x2 a, f32x2 b, f32x2 c) {
    f32x2 d; asm("v_pk_fma_f32 %0, %1, %2, %3" : "=v"(d) : "v"(a), "v"(b), "v"(c)); return d;
}
// two bf16 packed in a u32 -> f32 pair {lo, hi}
__device__ __forceinline__ f32x2 cvt2(unsigned u) {
    f32x2 r;
    r.x = __uint_as_float(u << 16);
    r.y = __uint_as_float(u & 0xffff0000u);
    return r;
}

// ---------------- CSR build: count + per-edge rank (atomic return value, coalesced store) ----------------
__global__ void count_kernel(const int* __restrict__ dst, int* __restrict__ cnt,
                             int* __restrict__ rank, int E, int n) {
    int i = blockIdx.x * blockDim.x + threadIdx.x;
    int e = i * 4;
    if (e + 3 < E) {
        int4 d4 = *(const int4*)(dst + e);
        int4 r4;
        r4.x = atomicAdd(&cnt[clampi(d4.x, 0, n - 1)], 1);
        r4.y = atomicAdd(&cnt[clampi(d4.y, 0, n - 1)], 1);
        r4.z = atomicAdd(&cnt[clampi(d4.z, 0, n - 1)], 1);
        r4.w = atomicAdd(&cnt[clampi(d4.w, 0, n - 1)], 1);
        *(int4*)(rank + e) = r4;
    } else {
        for (; e < E; ++e) rank[e] = atomicAdd(&cnt[clampi(dst[e], 0, n - 1)], 1);
    }
}

__global__ __launch_bounds__(256) void scan1_kernel(const int* __restrict__ cnt,
                                                    int* __restrict__ cursor,
                                                    int* __restrict__ bsum, int n) {
    __shared__ int wsum[4];
    const int tid = threadIdx.x, lane = tid & 63, wv = tid >> 6;
    int idx = blockIdx.x * 256 + tid;
    int v = (idx < n) ? cnt[idx] : 0;
    int s = v;
    #pragma unroll
    for (int off = 1; off < 64; off <<= 1) {
        int u = __shfl_up(s, off);
        if (lane >= off) s += u;
    }
    if (lane == 63) wsum[wv] = s;
    __syncthreads();
    int add = 0;
    for (int i = 0; i < wv; ++i) add += wsum[i];
    int incl = s + add;
    if (idx < n) cursor[idx] = incl - v;
    if (tid == 255) bsum[blockIdx.x] = incl;
}

__global__ __launch_bounds__(256) void scan2_kernel(int* __restrict__ bsum, int nb) {
    __shared__ int wsum[4];
    const int tid = threadIdx.x, lane = tid & 63, wv = tid >> 6;
    int carry = 0;
    for (int base = 0; base < nb; base += 256) {
        int idx = base + tid;
        int v = (idx < nb) ? bsum[idx] : 0;
        int s = v;
        #pragma unroll
        for (int off = 1; off < 64; off <<= 1) {
            int u = __shfl_up(s, off);
            if (lane >= off) s += u;
        }
        if (lane == 63) wsum[wv] = s;
        __syncthreads();
        int add = 0;
        for (int i = 0; i < wv; ++i) add += wsum[i];
        if (idx < nb) bsum[idx] = s + add + carry - v;
        int tot = wsum[0] + wsum[1] + wsum[2] + wsum[3];
        __syncthreads();
        carry += tot;
    }
}

// ---------------- weight conversion ----------------
__global__ void cvt_weights(const float* __restrict__ msg_w, const float* __restrict__ upd_w,
                            unsigned short* __restrict__ wtT, unsigned short* __restrict__ wbT,
                            unsigned short* __restrict__ wuT) {
    int tid = blockIdx.x * blockDim.x + threadIdx.x;   // 65536
    int m = tid >> 14;
    int r = tid & 16383;
    int d = r >> 7, k = r & 127;
    float v;
    unsigned short* dstp;
    if (m == 0)      { v = msg_w[k * 128 + d];          dstp = wtT; }
    else if (m == 1) { v = msg_w[(128 + k) * 128 + d];  dstp = wbT; }
    else if (m == 2) { v = upd_w[k * 128 + d];          dstp = wuT; }
    else             { v = upd_w[(128 + k) * 128 + d];  dstp = wuT + 16384; }
    dstp[d * 128 + k] = f2bf(v);
}

// ---------------- pre: tsrcb/tdstb + row sums + xb, fused ATOMIC-FREE scatter ----------------
__global__ __launch_bounds__(256) void pre_both_mfma(
    const float* __restrict__ x,
    const unsigned short* __restrict__ wtT, const unsigned short* __restrict__ wbT,
    const float* __restrict__ bias, unsigned short* __restrict__ xb,
    unsigned short* __restrict__ tsrcb, unsigned short* __restrict__ tdstb,
    float* __restrict__ saRow, float* __restrict__ stRow, int n,
    const int* __restrict__ src, const int* __restrict__ dst,
    const float* __restrict__ ew, const int* __restrict__ rank,
    const int* __restrict__ cursor, const int* __restrict__ boff,
    unsigned long long* __restrict__ swP, int E, int epb)
{
    __shared__ unsigned short Wt[16384];
    __shared__ unsigned short Wb[16384];
    const int tid = threadIdx.x, lane = tid & 63, wv = tid >> 6;
    const int dbase = lane & 15, kgrp = lane >> 4;
    const int swzl = (dbase & 7) << 4;
    const int r0 = blockIdx.x * 64;

    // hoisted edge loads + position computation (all independent; latency hides under MFMA)
    const int ebase = blockIdx.x * epb;
    const int eend  = imin(ebase + epb, E);
    int hp[4]; unsigned long long hv[4]; bool hvld[4];
    {
        #pragma unroll
        for (int u = 0; u < 4; ++u) {
            int ec = ebase + tid + u * 256;
            bool v = (ec < eend);
            int ecc = v ? ec : (E - 1);
            int d  = clampi(dst[ecc], 0, n - 1);
            int s  = clampi(src[ecc], 0, n - 1);
            hv[u]  = ((unsigned long long)__float_as_uint(ew[ecc]) << 32) | (unsigned)s;
            hp[u]  = boff[d >> 8] + cursor[d] + rank[ecc];
            hvld[u] = v;
        }
    }

    {
        const ushort8v* st = (const ushort8v*)wtT;
        const ushort8v* sb = (const ushort8v*)wbT;
        for (int c = tid; c < 2048; c += 256) {
            int d = c >> 4, slot = c & 15;
            int off = d * 256 + ((slot * 16) ^ ((d & 7) << 4));
            *(ushort8v*)((char*)Wt + off) = st[c];
            *(ushort8v*)((char*)Wb + off) = sb[c];
        }
    }

    int rowA = imin(r0 + wv * 16 + dbase, n - 1);
    bf16x8 a[4];
    {
        const float* xr = x + (size_t)rowA * H + kgrp * 8;
        #pragma unroll
        for (int s = 0; s < 4; ++s) {
            float4 f0 = *(const float4*)(xr + s * 32);
            float4 f1 = *(const float4*)(xr + s * 32 + 4);
            bf16x8 v;
            v[0] = (short)f2bf(f0.x); v[1] = (short)f2bf(f0.y);
            v[2] = (short)f2bf(f0.z); v[3] = (short)f2bf(f0.w);
            v[4] = (short)f2bf(f1.x); v[5] = (short)f2bf(f1.y);
            v[6] = (short)f2bf(f1.z); v[7] = (short)f2bf(f1.w);
            a[s] = v;
            *(bf16x8*)(xb + (size_t)rowA * H + s * 32 + kgrp * 8) = v;
        }
    }
    __syncthreads();

    f32x4 accT[8], accB[8];
    #pragma unroll
    for (int t = 0; t < 8; ++t) { accT[t] = (f32x4){0.f,0.f,0.f,0.f}; accB[t] = (f32x4){0.f,0.f,0.f,0.f}; }
    #pragma unroll
    for (int s = 0; s < 4; ++s) {
        #pragma unroll
        for (int t = 0; t < 8; ++t) {
            int off = (t * 16 + dbase) * 256 + ((s * 64 + kgrp * 16) ^ swzl);
            bf16x8 bt = *(const bf16x8*)((const char*)Wt + off);
            bf16x8 bb = *(const bf16x8*)((const char*)Wb + off);
            accT[t] = __builtin_amdgcn_mfma_f32_16x16x32_bf16(a[s], bt, accT[t], 0, 0, 0);
            accB[t] = __builtin_amdgcn_mfma_f32_16x16x32_bf16(a[s], bb, accB[t], 0, 0, 0);
        }
    }

    float ub[8];
    #pragma unroll
    for (int t = 0; t < 8; ++t) ub[t] = bias[t * 16 + dbase];
    #pragma unroll
    for (int r = 0; r < 4; ++r) {
        int row = r0 + wv * 16 + kgrp * 4 + r;
        if (row < n) {
            unsigned short sv[8], tv[8];
            float sa = 0.f, st = 0.f;
            #pragma unroll
            for (int t = 0; t < 8; ++t) {
                unsigned short av = f2bf(accT[t][r]);
                unsigned short dv = f2bf(accB[t][r] + ub[t]);
                sv[t] = av; tv[t] = dv;
                sa += bf2f(av); st += bf2f(dv);
            }
            #pragma unroll
            for (int t = 0; t < 8; ++t) {
                tsrcb[(size_t)row * H + t * 16 + dbase] = sv[t];
                tdstb[(size_t)row * H + t * 16 + dbase] = tv[t];
            }
            sa += __shfl_xor(sa, 1); st += __shfl_xor(st, 1);
            sa += __shfl_xor(sa, 2); st += __shfl_xor(st, 2);
            sa += __shfl_xor(sa, 4); st += __shfl_xor(st, 4);
            sa += __shfl_xor(sa, 8); st += __shfl_xor(st, 8);
            if (dbase == 0) { saRow[row] = sa; stRow[row] = st; }
        }
    }

    // scatter tail: pure fire-and-forget stores (positions precomputed, no atomics)
    {
        #pragma unroll
        for (int u = 0; u < 4; ++u)
            if (hvld[u]) swP[hp[u]] = hv[u];
        for (int ebb = ebase + 1024; ebb < eend; ebb += 1024) {
            #pragma unroll
            for (int u = 0; u < 4; ++u) {
                int ec = ebb + tid + u * 256;
                if (ec < eend) {
                    int d = clampi(dst[ec], 0, n - 1);
                    int s = clampi(src[ec], 0, n - 1);
                    int p = boff[d >> 8] + cursor[d] + rank[ec];
                    swP[p] = ((unsigned long long)__float_as_uint(ew[ec]) << 32) | (unsigned)s;
                }
            }
        }
    }
}

// ---------------- node-centric messages: one wave per node, packed dual-f32 math ----------------
__global__ __launch_bounds__(256) void node_msg_kernel(
    const unsigned short* __restrict__ tsrcb,
    const unsigned short* __restrict__ tdstb,
    const float* __restrict__ saRow, const float* __restrict__ stRow,
    const unsigned long long* __restrict__ swP,
    const int* __restrict__ cnt, const int* __restrict__ cursor,
    const int* __restrict__ boff,
    const float* __restrict__ gamma, const float* __restrict__ beta,
    unsigned short* __restrict__ msgsb, int n)
{
    const int tid  = threadIdx.x;
    const int lane = tid & 63;
    const int grp  = lane >> 4;               // edge slot 0..3 within the wave
    const int qq   = lane & 15;               // dims qq*8 .. qq*8+7
    const int node = blockIdx.x * 4 + (tid >> 6);
    if (node >= n) return;
    const int k   = cnt[node];                // wave-uniform
    const int e0  = boff[node >> 8] + cursor[node];

    f32x2 td2[4];
    {
        uint4v t = *(const uint4v*)(tdstb + (size_t)node * H + qq * 8);
        #pragma unroll
        for (int p = 0; p < 4; ++p) td2[p] = cvt2(t[p]);
    }
    const float St = stRow[node];
    f32x2 g2[4], b2[4];
    #pragma unroll
    for (int p = 0; p < 4; ++p) {
        g2[p].x = gamma[qq * 8 + 2 * p];     g2[p].y = gamma[qq * 8 + 2 * p + 1];
        b2[p].x = beta[qq * 8 + 2 * p];      b2[p].y = beta[qq * 8 + 2 * p + 1];
    }

    f32x2 acc2[4];
    #pragma unroll
    for (int p = 0; p < 4; ++p) acc2[p] = (f32x2){0.f, 0.f};

    uint4v A0 = {};
    float W0 = 0.f, S0 = 0.f;
    if (grp < k) {
        unsigned long long sw = swP[e0 + grp];
        int s = (int)(unsigned)sw; W0 = __uint_as_float((unsigned)(sw >> 32));
        S0 = saRow[s]; A0 = *(const uint4v*)(tsrcb + (size_t)s * H + qq * 8);
    }

    for (int i = 0; i < k; i += 4) {
        uint4v A1 = {};
        float W1 = 0.f, S1 = 0.f;
        int jn = i + 4 + grp;
        if (jn < k) {
            unsigned long long sw = swP[e0 + jn];
            int s = (int)(unsigned)sw; W1 = __uint_as_float((unsigned)(sw >> 32));
            S1 = saRow[s]; A1 = *(const uint4v*)(tsrcb + (size_t)s * H + qq * 8);
        }

        f32x2 v2[4];
        f32x2 sq2 = (f32x2){0.f, 0.f};
        #pragma unroll
        for (int p = 0; p < 4; ++p) {
            v2[p] = pk_add(td2[p], cvt2(A0[p]));
            sq2 = pk_fma(v2[p], v2[p], sq2);
        }
        float sq = sq2.x + sq2.y;
        sq += __shfl_xor(sq, 1);
        sq += __shfl_xor(sq, 2);
        sq += __shfl_xor(sq, 4);
        sq += __shfl_xor(sq, 8);

        float mu  = (S0 + St) * (1.f / 128.f);
        float var = sq * (1.f / 128.f) - mu * mu;
        float ri  = rsqrtf(fmaxf(var, 0.f) + LN_EPS);
        float nmr = -mu * ri;
        f32x2 riS  = (f32x2){ri, ri};
        f32x2 nmrS = (f32x2){nmr, nmr};
        f32x2 wS_  = (f32x2){W0, W0};
        #pragma unroll
        for (int p = 0; p < 4; ++p) {
            f32x2 t2  = pk_fma(v2[p], riS, nmrS);
            f32x2 val = pk_fma(t2, g2[p], b2[p]);
            val.x = fmaxf(val.x, 0.f);
            val.y = fmaxf(val.y, 0.f);
            acc2[p] = pk_fma(val, wS_, acc2[p]);     // W0==0 for invalid slots
        }
        A0 = A1; W0 = W1; S0 = S1;
    }

    // cross-group reduction: sum the 4 edge-slot partials for each dim
    #pragma unroll
    for (int p = 0; p < 4; ++p) {
        acc2[p].x += __shfl_xor(acc2[p].x, 16);
        acc2[p].y += __shfl_xor(acc2[p].y, 16);
        acc2[p].x += __shfl_xor(acc2[p].x, 32);
        acc2[p].y += __shfl_xor(acc2[p].y, 32);
    }

    if (grp == 0) {
        float scale = (k > 0) ? 1.f / ((float)k + 1e-8f) : 0.f;
        ushort8v o;
        #pragma unroll
        for (int p = 0; p < 4; ++p) {
            o[2 * p]     = f2bf(acc2[p].x * scale);
            o[2 * p + 1] = f2bf(acc2[p].y * scale);
        }
        *(ushort8v*)(msgsb + (size_t)node * H + qq * 8) = o;
    }
}

// ---------------- update via MFMA ----------------
__global__ __launch_bounds__(256) void update_mfma(
    const unsigned short* __restrict__ xb,
    const unsigned short* __restrict__ msgsb,
    const unsigned short* __restrict__ wuT,
    const float* __restrict__ upd_b, const float* __restrict__ g,
    const float* __restrict__ beta, const float* __restrict__ gate_w,
    const float* __restrict__ gate_b, float* __restrict__ out, int n)
{
    __shared__ unsigned short W2[2][16384];   // 64 KB
    const int tid = threadIdx.x, lane = tid & 63, wv = tid >> 6;
    const int dbase = lane & 15, kgrp = lane >> 4;
    const int swzl = (dbase & 7) << 4;
    const int r0 = blockIdx.x * 64;

    {
        const ushort8v* srcp = (const ushort8v*)wuT;
        for (int c = tid; c < 4096; c += 256) {
            int m = c >> 11, c2 = c & 2047;
            int d = c2 >> 4, slot = c2 & 15;
            int off = m * 32768 + d * 256 + ((slot * 16) ^ ((d & 7) << 4));
            *(ushort8v*)((char*)W2 + off) = srcp[c];
        }
    }

    int rowA = imin(r0 + wv * 16 + dbase, n - 1);
    bf16x8 ax[4], am[4];
    {
        const char* arow = (const char*)(xb + (size_t)rowA * H) + kgrp * 16;
        const char* mrow = (const char*)(msgsb + (size_t)rowA * H) + kgrp * 16;
        #pragma unroll
        for (int s = 0; s < 4; ++s) {
            ax[s] = *(const bf16x8*)(arow + s * 64);
            am[s] = *(const bf16x8*)(mrow + s * 64);
        }
    }
    __syncthreads();

    f32x4 acc[8];
    #pragma unroll
    for (int t = 0; t < 8; ++t) acc[t] = (f32x4){0.f, 0.f, 0.f, 0.f};
    #pragma unroll
    for (int s = 0; s < 4; ++s) {
        #pragma unroll
        for (int t = 0; t < 8; ++t) {
            int off = (t * 16 + dbase) * 256 + ((s * 64 + kgrp * 16) ^ swzl);
            bf16x8 b = *(const bf16x8*)((const char*)W2 + off);
            acc[t] = __builtin_amdgcn_mfma_f32_16x16x32_bf16(ax[s], b, acc[t], 0, 0, 0);
        }
    }
    #pragma unroll
    for (int s = 0; s < 4; ++s) {
        #pragma unroll
        for (int t = 0; t < 8; ++t) {
            int off = 32768 + (t * 16 + dbase) * 256 + ((s * 64 + kgrp * 16) ^ swzl);
            bf16x8 b = *(const bf16x8*)((const char*)W2 + off);
            acc[t] = __builtin_amdgcn_mfma_f32_16x16x32_bf16(am[s], b, acc[t], 0, 0, 0);
        }
    }

    float ub[8], g_[8], be_[8], gw_[8];
    #pragma unroll
    for (int t = 0; t < 8; ++t) {
        int d = t * 16 + dbase;
        ub[t] = upd_b[d]; g_[t] = g[d]; be_[t] = beta[d]; gw_[t] = gate_w[d];
    }
    const float gb = gate_b[0];

    #pragma unroll
    for (int r = 0; r < 4; ++r) {
        int row = r0 + wv * 16 + kgrp * 4 + r;
        if (row >= n) continue;
        const unsigned short* xr = xb + (size_t)row * H + dbase;
        float xf[8], v[8];
        float sum = 0.f, sq = 0.f, gs = 0.f;
        #pragma unroll
        for (int t = 0; t < 8; ++t) {
            xf[t] = bf2f(xr[t * 16]);
            float val = acc[t][r] + ub[t];
            v[t] = val;
            sum += val;
            sq = fmaf(val, val, sq);
            gs = fmaf(xf[t], gw_[t], gs);
        }
        sum += __shfl_xor(sum, 1); sq += __shfl_xor(sq, 1); gs += __shfl_xor(gs, 1);
        sum += __shfl_xor(sum, 2); sq += __shfl_xor(sq, 2); gs += __shfl_xor(gs, 2);
        sum += __shfl_xor(sum, 4); sq += __shfl_xor(sq, 4); gs += __shfl_xor(gs, 4);
        sum += __shfl_xor(sum, 8); sq += __shfl_xor(sq, 8); gs += __shfl_xor(gs, 8);
        float mu  = sum * (1.f / 128.f);
        float var = sq * (1.f / 128.f) - mu * mu;
        float ri  = rsqrtf(fmaxf(var, 0.f) + LN_EPS);
        float gate = 1.f / (1.f + expf(-(gs + gb)));
        float* orow = out + (size_t)row * H + dbase;
        #pragma unroll
        for (int t = 0; t < 8; ++t) {
            float h = fmaf((v[t] - mu) * ri, g_[t], be_[t]);
            h = fmaxf(h, 0.f);
            orow[t * 16] = fmaf(gate, h - xf[t], xf[t]);
        }
    }
}

extern "C" void kernel_launch(void* const* d_in, const int* in_sizes, int n_in,
                              void* d_out, int out_size, void* d_ws, size_t ws_size,
                              hipStream_t stream)
{
    const float* x        = (const float*)d_in[0];
    const int*   ei       = (const int*)d_in[1];
    const float* ew       = (const float*)d_in[2];
    const float* msg_w    = (const float*)d_in[3];
    const float* msg_b    = (const float*)d_in[4];
    const float* msg_g    = (const float*)d_in[5];
    const float* msg_beta = (const float*)d_in[6];
    const float* upd_w    = (const float*)d_in[7];
    const float* upd_b    = (const float*)d_in[8];
    const float* upd_g    = (const float*)d_in[9];
    const float* upd_beta = (const float*)d_in[10];
    const float* gate_w   = (const float*)d_in[11];
    const float* gate_b   = (const float*)d_in[12];

    const int n = in_sizes[0] / H;
    const int E = in_sizes[2];
    const int* src = ei;
    const int* dst = ei + E;

    char* p = (char*)d_ws;
    auto alloc = [&](size_t bytes) { char* r = p; p += (bytes + 255) & ~(size_t)255; return r; };
    int*   cnt    = (int*)alloc((size_t)n * 4);
    int*   cursor = (int*)alloc((size_t)n * 4);
    int*   bsum   = (int*)alloc((size_t)1024 * 4);
    int*   rank   = (int*)alloc((size_t)E * 4);
    unsigned long long* swP = (unsigned long long*)alloc((size_t)E * 8);
    float* saRow  = (float*)alloc((size_t)n * 4);
    float* stRow  = (float*)alloc((size_t)n * 4);
    unsigned short* xb    = (unsigned short*)alloc((size_t)n * H * 2);
    unsigned short* tsrcb = (unsigned short*)alloc((size_t)n * H * 2);
    unsigned short* tdstb = (unsigned short*)alloc((size_t)n * H * 2);
    unsigned short* msgsb = (unsigned short*)alloc((size_t)n * H * 2);
    unsigned short* wtT   = (unsigned short*)alloc((size_t)H * H * 2);
    unsigned short* wbT   = (unsigned short*)alloc((size_t)H * H * 2);
    unsigned short* wuT   = (unsigned short*)alloc((size_t)2 * H * H * 2);

    hipMemsetAsync(cnt, 0, (size_t)n * 4, stream);

    const int nb = (n + 255) / 256;
    int eb4 = ((E + 3) / 4 + 255) / 256;
    count_kernel<<<eb4, 256, 0, stream>>>(dst, cnt, rank, E, n);
    scan1_kernel<<<nb, 256, 0, stream>>>(cnt, cursor, bsum, n);
    scan2_kernel<<<1, 256, 0, stream>>>(bsum, nb);

    cvt_weights<<<256, 256, 0, stream>>>(msg_w, upd_w, wtT, wbT, wuT);

    const int nblocks = (n + 63) / 64;
    const int epb = (E + nblocks - 1) / nblocks;
    pre_both_mfma<<<nblocks, 256, 0, stream>>>(x, wtT, wbT, msg_b, xb, tsrcb, tdstb,
                                               saRow, stRow, n,
                                               src, dst, ew, rank, cursor, bsum, swP, E, epb);

    node_msg_kernel<<<(n + 3) / 4, 256, 0, stream>>>(tsrcb, tdstb, saRow, stRow, swP,
                                                     cnt, cursor, bsum,
                                                     msg_g, msg_beta, msgsb, n);

    update_mfma<<<(n + 63) / 64, 256, 0, stream>>>(xb, msgsb, wuT, upd_b, upd_g, upd_beta,
                                                   gate_w, gate_b, (float*)d_out, n);
}

// Round 17
// 151.036 us; speedup vs baseline: 1.0325x; 1.0325x over previous
//
#include <hip/hip_runtime.h>
#include <math.h>

#define H 128
#define LN_EPS 1e-5f

typedef __attribute__((ext_vector_type(8))) short  bf16x8;
typedef __attribute__((ext_vector_type(4))) float  f32x4;
typedef __attribute__((ext_vector_type(8))) unsigned short ushort8v;

__device__ __forceinline__ int imin(int a, int b) { return a < b ? a : b; }
__device__ __forceinline__ int clampi(int v, int lo, int hi) { return v < lo ? lo : (v > hi ? hi : v); }
__device__ __forceinline__ unsigned short f2bf(float f) {
    unsigned u = __float_as_uint(f);
    unsigned r = (u + 0x7fffu + ((u >> 16) & 1u)) >> 16;   // RNE
    return (unsigned short)r;
}
__device__ __forceinline__ float bf2f(unsigned short u) {
    return __uint_as_float(((unsigned)u) << 16);
}

// ---------------- CSR build: count + per-edge rank (atomic return value, coalesced store) ----------------
__global__ void count_kernel(const int* __restrict__ dst, int* __restrict__ cnt,
                             int* __restrict__ rank, int E, int n) {
    int i = blockIdx.x * blockDim.x + threadIdx.x;
    int e = i * 4;
    if (e + 3 < E) {
        int4 d4 = *(const int4*)(dst + e);
        int4 r4;
        r4.x = atomicAdd(&cnt[clampi(d4.x, 0, n - 1)], 1);
        r4.y = atomicAdd(&cnt[clampi(d4.y, 0, n - 1)], 1);
        r4.z = atomicAdd(&cnt[clampi(d4.z, 0, n - 1)], 1);
        r4.w = atomicAdd(&cnt[clampi(d4.w, 0, n - 1)], 1);
        *(int4*)(rank + e) = r4;
    } else {
        for (; e < E; ++e) rank[e] = atomicAdd(&cnt[clampi(dst[e], 0, n - 1)], 1);
    }
}

// per-node exclusive prefix within its 256-node bucket (READ-ONLY afterwards); bsum[b] = bucket total
__global__ __launch_bounds__(256) void scan1_kernel(const int* __restrict__ cnt,
                                                    int* __restrict__ cursor,
                                                    int* __restrict__ bsum, int n) {
    __shared__ int wsum[4];
    const int tid = threadIdx.x, lane = tid & 63, wv = tid >> 6;
    int idx = blockIdx.x * 256 + tid;
    int v = (idx < n) ? cnt[idx] : 0;
    int s = v;
    #pragma unroll
    for (int off = 1; off < 64; off <<= 1) {
        int u = __shfl_up(s, off);
        if (lane >= off) s += u;
    }
    if (lane == 63) wsum[wv] = s;
    __syncthreads();
    int add = 0;
    for (int i = 0; i < wv; ++i) add += wsum[i];
    int incl = s + add;
    if (idx < n) cursor[idx] = incl - v;
    if (tid == 255) bsum[blockIdx.x] = incl;
}

__global__ __launch_bounds__(256) void scan2_kernel(int* __restrict__ bsum, int nb) {
    __shared__ int wsum[4];
    const int tid = threadIdx.x, lane = tid & 63, wv = tid >> 6;
    int carry = 0;
    for (int base = 0; base < nb; base += 256) {
        int idx = base + tid;
        int v = (idx < nb) ? bsum[idx] : 0;
        int s = v;
        #pragma unroll
        for (int off = 1; off < 64; off <<= 1) {
            int u = __shfl_up(s, off);
            if (lane >= off) s += u;
        }
        if (lane == 63) wsum[wv] = s;
        __syncthreads();
        int add = 0;
        for (int i = 0; i < wv; ++i) add += wsum[i];
        if (idx < nb) bsum[idx] = s + add + carry - v;
        int tot = wsum[0] + wsum[1] + wsum[2] + wsum[3];
        __syncthreads();
        carry += tot;
    }
}

// ---------------- weight conversion ----------------
__global__ void cvt_weights(const float* __restrict__ msg_w, const float* __restrict__ upd_w,
                            unsigned short* __restrict__ wtT, unsigned short* __restrict__ wbT,
                            unsigned short* __restrict__ wuT) {
    int tid = blockIdx.x * blockDim.x + threadIdx.x;   // 65536
    int m = tid >> 14;
    int r = tid & 16383;
    int d = r >> 7, k = r & 127;
    float v;
    unsigned short* dstp;
    if (m == 0)      { v = msg_w[k * 128 + d];          dstp = wtT; }
    else if (m == 1) { v = msg_w[(128 + k) * 128 + d];  dstp = wbT; }
    else if (m == 2) { v = upd_w[k * 128 + d];          dstp = wuT; }
    else             { v = upd_w[(128 + k) * 128 + d];  dstp = wuT + 16384; }
    dstp[d * 128 + k] = f2bf(v);
}

// ---------------- pre: tsrcb/tdstb + row sums + xb, fused ATOMIC-FREE scatter ----------------
__global__ __launch_bounds__(256) void pre_both_mfma(
    const float* __restrict__ x,
    const unsigned short* __restrict__ wtT, const unsigned short* __restrict__ wbT,
    const float* __restrict__ bias, unsigned short* __restrict__ xb,
    unsigned short* __restrict__ tsrcb, unsigned short* __restrict__ tdstb,
    float* __restrict__ saRow, float* __restrict__ stRow, int n,
    const int* __restrict__ src, const int* __restrict__ dst,
    const float* __restrict__ ew, const int* __restrict__ rank,
    const int* __restrict__ cursor, const int* __restrict__ boff,
    unsigned long long* __restrict__ swP, int E, int epb)
{
    __shared__ unsigned short Wt[16384];
    __shared__ unsigned short Wb[16384];
    const int tid = threadIdx.x, lane = tid & 63, wv = tid >> 6;
    const int dbase = lane & 15, kgrp = lane >> 4;
    const int swzl = (dbase & 7) << 4;
    const int r0 = blockIdx.x * 64;

    // hoisted edge loads + position computation (all independent; latency hides under MFMA)
    const int ebase = blockIdx.x * epb;
    const int eend  = imin(ebase + epb, E);
    int hp[4]; unsigned long long hv[4]; bool hvld[4];
    {
        #pragma unroll
        for (int u = 0; u < 4; ++u) {
            int ec = ebase + tid + u * 256;
            bool v = (ec < eend);
            int ecc = v ? ec : (E - 1);
            int d  = clampi(dst[ecc], 0, n - 1);
            int s  = clampi(src[ecc], 0, n - 1);
            hv[u]  = ((unsigned long long)__float_as_uint(ew[ecc]) << 32) | (unsigned)s;
            hp[u]  = boff[d >> 8] + cursor[d] + rank[ecc];
            hvld[u] = v;
        }
    }

    {
        const ushort8v* st = (const ushort8v*)wtT;
        const ushort8v* sb = (const ushort8v*)wbT;
        for (int c = tid; c < 2048; c += 256) {
            int d = c >> 4, slot = c & 15;
            int off = d * 256 + ((slot * 16) ^ ((d & 7) << 4));
            *(ushort8v*)((char*)Wt + off) = st[c];
            *(ushort8v*)((char*)Wb + off) = sb[c];
        }
    }

    int rowA = imin(r0 + wv * 16 + dbase, n - 1);
    bf16x8 a[4];
    {
        const float* xr = x + (size_t)rowA * H + kgrp * 8;
        #pragma unroll
        for (int s = 0; s < 4; ++s) {
            float4 f0 = *(const float4*)(xr + s * 32);
            float4 f1 = *(const float4*)(xr + s * 32 + 4);
            bf16x8 v;
            v[0] = (short)f2bf(f0.x); v[1] = (short)f2bf(f0.y);
            v[2] = (short)f2bf(f0.z); v[3] = (short)f2bf(f0.w);
            v[4] = (short)f2bf(f1.x); v[5] = (short)f2bf(f1.y);
            v[6] = (short)f2bf(f1.z); v[7] = (short)f2bf(f1.w);
            a[s] = v;
            *(bf16x8*)(xb + (size_t)rowA * H + s * 32 + kgrp * 8) = v;
        }
    }
    __syncthreads();

    f32x4 accT[8], accB[8];
    #pragma unroll
    for (int t = 0; t < 8; ++t) { accT[t] = (f32x4){0.f,0.f,0.f,0.f}; accB[t] = (f32x4){0.f,0.f,0.f,0.f}; }
    #pragma unroll
    for (int s = 0; s < 4; ++s) {
        #pragma unroll
        for (int t = 0; t < 8; ++t) {
            int off = (t * 16 + dbase) * 256 + ((s * 64 + kgrp * 16) ^ swzl);
            bf16x8 bt = *(const bf16x8*)((const char*)Wt + off);
            bf16x8 bb = *(const bf16x8*)((const char*)Wb + off);
            accT[t] = __builtin_amdgcn_mfma_f32_16x16x32_bf16(a[s], bt, accT[t], 0, 0, 0);
            accB[t] = __builtin_amdgcn_mfma_f32_16x16x32_bf16(a[s], bb, accB[t], 0, 0, 0);
        }
    }

    float ub[8];
    #pragma unroll
    for (int t = 0; t < 8; ++t) ub[t] = bias[t * 16 + dbase];
    #pragma unroll
    for (int r = 0; r < 4; ++r) {
        int row = r0 + wv * 16 + kgrp * 4 + r;
        if (row < n) {
            unsigned short sv[8], tv[8];
            float sa = 0.f, st = 0.f;
            #pragma unroll
            for (int t = 0; t < 8; ++t) {
                unsigned short av = f2bf(accT[t][r]);
                unsigned short dv = f2bf(accB[t][r] + ub[t]);
                sv[t] = av; tv[t] = dv;
                sa += bf2f(av); st += bf2f(dv);
            }
            #pragma unroll
            for (int t = 0; t < 8; ++t) {
                tsrcb[(size_t)row * H + t * 16 + dbase] = sv[t];
                tdstb[(size_t)row * H + t * 16 + dbase] = tv[t];
            }
            sa += __shfl_xor(sa, 1); st += __shfl_xor(st, 1);
            sa += __shfl_xor(sa, 2); st += __shfl_xor(st, 2);
            sa += __shfl_xor(sa, 4); st += __shfl_xor(st, 4);
            sa += __shfl_xor(sa, 8); st += __shfl_xor(st, 8);
            if (dbase == 0) { saRow[row] = sa; stRow[row] = st; }
        }
    }

    // scatter tail: pure fire-and-forget stores (positions precomputed, no atomics)
    {
        #pragma unroll
        for (int u = 0; u < 4; ++u)
            if (hvld[u]) swP[hp[u]] = hv[u];
        for (int ebb = ebase + 1024; ebb < eend; ebb += 1024) {
            #pragma unroll
            for (int u = 0; u < 4; ++u) {
                int ec = ebb + tid + u * 256;
                if (ec < eend) {
                    int d = clampi(dst[ec], 0, n - 1);
                    int s = clampi(src[ec], 0, n - 1);
                    int p = boff[d >> 8] + cursor[d] + rank[ec];
                    swP[p] = ((unsigned long long)__float_as_uint(ew[ec]) << 32) | (unsigned)s;
                }
            }
        }
    }
}

// ---------------- node-centric messages: one wave per node (4 edges/iter), bf16 out ----------------
__global__ __launch_bounds__(256) void node_msg_kernel(
    const unsigned short* __restrict__ tsrcb,
    const unsigned short* __restrict__ tdstb,
    const float* __restrict__ saRow, const float* __restrict__ stRow,
    const unsigned long long* __restrict__ swP,
    const int* __restrict__ cnt, const int* __restrict__ cursor,
    const int* __restrict__ boff,
    const float* __restrict__ gamma, const float* __restrict__ beta,
    unsigned short* __restrict__ msgsb, int n)
{
    const int tid  = threadIdx.x;
    const int lane = tid & 63;
    const int grp  = lane >> 4;               // edge slot 0..3 within the wave
    const int qq   = lane & 15;               // dims qq*8 .. qq*8+7
    const int node = blockIdx.x * 4 + (tid >> 6);
    if (node >= n) return;
    const int k   = cnt[node];                // wave-uniform
    const int e0  = boff[node >> 8] + cursor[node];

    float td[8];
    {
        ushort8v t = *(const ushort8v*)(tdstb + (size_t)node * H + qq * 8);
        #pragma unroll
        for (int j = 0; j < 8; ++j) td[j] = bf2f((unsigned short)t[j]);
    }
    const float St = stRow[node];
    float g_[8], b_[8];
    #pragma unroll
    for (int j = 0; j < 8; ++j) { g_[j] = gamma[qq * 8 + j]; b_[j] = beta[qq * 8 + j]; }

    float acc[8];
    #pragma unroll
    for (int j = 0; j < 8; ++j) acc[j] = 0.f;

    ushort8v A0 = {};
    float W0 = 0.f, S0 = 0.f;
    if (grp < k) {
        unsigned long long sw = swP[e0 + grp];
        int s = (int)(unsigned)sw; W0 = __uint_as_float((unsigned)(sw >> 32));
        S0 = saRow[s]; A0 = *(const ushort8v*)(tsrcb + (size_t)s * H + qq * 8);
    }

    for (int i = 0; i < k; i += 4) {
        ushort8v A1 = {};
        float W1 = 0.f, S1 = 0.f;
        int jn = i + 4 + grp;
        if (jn < k) {
            unsigned long long sw = swP[e0 + jn];
            int s = (int)(unsigned)sw; W1 = __uint_as_float((unsigned)(sw >> 32));
            S1 = saRow[s]; A1 = *(const ushort8v*)(tsrcb + (size_t)s * H + qq * 8);
        }

        float v[8], sq = 0.f;
        #pragma unroll
        for (int j = 0; j < 8; ++j) {
            v[j] = td[j] + bf2f((unsigned short)A0[j]);
            sq = fmaf(v[j], v[j], sq);
        }
        sq += __shfl_xor(sq, 1);
        sq += __shfl_xor(sq, 2);
        sq += __shfl_xor(sq, 4);
        sq += __shfl_xor(sq, 8);

        float mu  = (S0 + St) * (1.f / 128.f);
        float var = sq * (1.f / 128.f) - mu * mu;
        float ri  = rsqrtf(fmaxf(var, 0.f) + LN_EPS);
        float nmr = -mu * ri;
        #pragma unroll
        for (int j = 0; j < 8; ++j) {
            float t = fmaf(v[j], ri, nmr);
            float val = fmaf(t, g_[j], b_[j]);
            acc[j] = fmaf(fmaxf(val, 0.f), W0, acc[j]);   // W0==0 for invalid slots
        }
        A0 = A1; W0 = W1; S0 = S1;
    }

    #pragma unroll
    for (int j = 0; j < 8; ++j) {
        acc[j] += __shfl_xor(acc[j], 16);
        acc[j] += __shfl_xor(acc[j], 32);
    }

    if (grp == 0) {
        float scale = (k > 0) ? 1.f / ((float)k + 1e-8f) : 0.f;
        ushort8v o;
        #pragma unroll
        for (int j = 0; j < 8; ++j) o[j] = f2bf(acc[j] * scale);
        *(ushort8v*)(msgsb + (size_t)node * H + qq * 8) = o;
    }
}

// ---------------- update via MFMA ----------------
__global__ __launch_bounds__(256) void update_mfma(
    const unsigned short* __restrict__ xb,
    const unsigned short* __restrict__ msgsb,
    const unsigned short* __restrict__ wuT,
    const float* __restrict__ upd_b, const float* __restrict__ g,
    const float* __restrict__ beta, const float* __restrict__ gate_w,
    const float* __restrict__ gate_b, float* __restrict__ out, int n)
{
    __shared__ unsigned short W2[2][16384];   // 64 KB
    const int tid = threadIdx.x, lane = tid & 63, wv = tid >> 6;
    const int dbase = lane & 15, kgrp = lane >> 4;
    const int swzl = (dbase & 7) << 4;
    const int r0 = blockIdx.x * 64;

    {
        const ushort8v* srcp = (const ushort8v*)wuT;
        for (int c = tid; c < 4096; c += 256) {
            int m = c >> 11, c2 = c & 2047;
            int d = c2 >> 4, slot = c2 & 15;
            int off = m * 32768 + d * 256 + ((slot * 16) ^ ((d & 7) << 4));
            *(ushort8v*)((char*)W2 + off) = srcp[c];
        }
    }

    int rowA = imin(r0 + wv * 16 + dbase, n - 1);
    bf16x8 ax[4], am[4];
    {
        const char* arow = (const char*)(xb + (size_t)rowA * H) + kgrp * 16;
        const char* mrow = (const char*)(msgsb + (size_t)rowA * H) + kgrp * 16;
        #pragma unroll
        for (int s = 0; s < 4; ++s) {
            ax[s] = *(const bf16x8*)(arow + s * 64);
            am[s] = *(const bf16x8*)(mrow + s * 64);
        }
    }
    __syncthreads();

    f32x4 acc[8];
    #pragma unroll
    for (int t = 0; t < 8; ++t) acc[t] = (f32x4){0.f, 0.f, 0.f, 0.f};
    #pragma unroll
    for (int s = 0; s < 4; ++s) {
        #pragma unroll
        for (int t = 0; t < 8; ++t) {
            int off = (t * 16 + dbase) * 256 + ((s * 64 + kgrp * 16) ^ swzl);
            bf16x8 b = *(const bf16x8*)((const char*)W2 + off);
            acc[t] = __builtin_amdgcn_mfma_f32_16x16x32_bf16(ax[s], b, acc[t], 0, 0, 0);
        }
    }
    #pragma unroll
    for (int s = 0; s < 4; ++s) {
        #pragma unroll
        for (int t = 0; t < 8; ++t) {
            int off = 32768 + (t * 16 + dbase) * 256 + ((s * 64 + kgrp * 16) ^ swzl);
            bf16x8 b = *(const bf16x8*)((const char*)W2 + off);
            acc[t] = __builtin_amdgcn_mfma_f32_16x16x32_bf16(am[s], b, acc[t], 0, 0, 0);
        }
    }

    float ub[8], g_[8], be_[8], gw_[8];
    #pragma unroll
    for (int t = 0; t < 8; ++t) {
        int d = t * 16 + dbase;
        ub[t] = upd_b[d]; g_[t] = g[d]; be_[t] = beta[d]; gw_[t] = gate_w[d];
    }
    const float gb = gate_b[0];

    #pragma unroll
    for (int r = 0; r < 4; ++r) {
        int row = r0 + wv * 16 + kgrp * 4 + r;
        if (row >= n) continue;
        const unsigned short* xr = xb + (size_t)row * H + dbase;
        float xf[8], v[8];
        float sum = 0.f, sq = 0.f, gs = 0.f;
        #pragma unroll
        for (int t = 0; t < 8; ++t) {
            xf[t] = bf2f(xr[t * 16]);
            float val = acc[t][r] + ub[t];
            v[t] = val;
            sum += val;
            sq = fmaf(val, val, sq);
            gs = fmaf(xf[t], gw_[t], gs);
        }
        sum += __shfl_xor(sum, 1); sq += __shfl_xor(sq, 1); gs += __shfl_xor(gs, 1);
        sum += __shfl_xor(sum, 2); sq += __shfl_xor(sq, 2); gs += __shfl_xor(gs, 2);
        sum += __shfl_xor(sum, 4); sq += __shfl_xor(sq, 4); gs += __shfl_xor(gs, 4);
        sum += __shfl_xor(sum, 8); sq += __shfl_xor(sq, 8); gs += __shfl_xor(gs, 8);
        float mu  = sum * (1.f / 128.f);
        float var = sq * (1.f / 128.f) - mu * mu;
        float ri  = rsqrtf(fmaxf(var, 0.f) + LN_EPS);
        float gate = 1.f / (1.f + expf(-(gs + gb)));
        float* orow = out + (size_t)row * H + dbase;
        #pragma unroll
        for (int t = 0; t < 8; ++t) {
            float h = fmaf((v[t] - mu) * ri, g_[t], be_[t]);
            h = fmaxf(h, 0.f);
            orow[t * 16] = fmaf(gate, h - xf[t], xf[t]);
        }
    }
}

extern "C" void kernel_launch(void* const* d_in, const int* in_sizes, int n_in,
                              void* d_out, int out_size, void* d_ws, size_t ws_size,
                              hipStream_t stream)
{
    const float* x        = (const float*)d_in[0];
    const int*   ei       = (const int*)d_in[1];
    const float* ew       = (const float*)d_in[2];
    const float* msg_w    = (const float*)d_in[3];
    const float* msg_b    = (const float*)d_in[4];
    const float* msg_g    = (const float*)d_in[5];
    const float* msg_beta = (const float*)d_in[6];
    const float* upd_w    = (const float*)d_in[7];
    const float* upd_b    = (const float*)d_in[8];
    const float* upd_g    = (const float*)d_in[9];
    const float* upd_beta = (const float*)d_in[10];
    const float* gate_w   = (const float*)d_in[11];
    const float* gate_b   = (const float*)d_in[12];

    const int n = in_sizes[0] / H;
    const int E = in_sizes[2];
    const int* src = ei;
    const int* dst = ei + E;

    char* p = (char*)d_ws;
    auto alloc = [&](size_t bytes) { char* r = p; p += (bytes + 255) & ~(size_t)255; return r; };
    int*   cnt    = (int*)alloc((size_t)n * 4);
    int*   cursor = (int*)alloc((size_t)n * 4);
    int*   bsum   = (int*)alloc((size_t)1024 * 4);
    int*   rank   = (int*)alloc((size_t)E * 4);
    unsigned long long* swP = (unsigned long long*)alloc((size_t)E * 8);
    float* saRow  = (float*)alloc((size_t)n * 4);
    float* stRow  = (float*)alloc((size_t)n * 4);
    unsigned short* xb    = (unsigned short*)alloc((size_t)n * H * 2);
    unsigned short* tsrcb = (unsigned short*)alloc((size_t)n * H * 2);
    unsigned short* tdstb = (unsigned short*)alloc((size_t)n * H * 2);
    unsigned short* msgsb = (unsigned short*)alloc((size_t)n * H * 2);
    unsigned short* wtT   = (unsigned short*)alloc((size_t)H * H * 2);
    unsigned short* wbT   = (unsigned short*)alloc((size_t)H * H * 2);
    unsigned short* wuT   = (unsigned short*)alloc((size_t)2 * H * H * 2);

    hipMemsetAsync(cnt, 0, (size_t)n * 4, stream);

    const int nb = (n + 255) / 256;
    int eb4 = ((E + 3) / 4 + 255) / 256;
    count_kernel<<<eb4, 256, 0, stream>>>(dst, cnt, rank, E, n);
    scan1_kernel<<<nb, 256, 0, stream>>>(cnt, cursor, bsum, n);
    scan2_kernel<<<1, 256, 0, stream>>>(bsum, nb);

    cvt_weights<<<256, 256, 0, stream>>>(msg_w, upd_w, wtT, wbT, wuT);

    const int nblocks = (n + 63) / 64;
    const int epb = (E + nblocks - 1) / nblocks;
    pre_both_mfma<<<nblocks, 256, 0, stream>>>(x, wtT, wbT, msg_b, xb, tsrcb, tdstb,
                                               saRow, stRow, n,
                                               src, dst, ew, rank, cursor, bsum, swP, E, epb);

    node_msg_kernel<<<(n + 3) / 4, 256, 0, stream>>>(tsrcb, tdstb, saRow, stRow, swP,
                                                     cnt, cursor, bsum,
                                                     msg_g, msg_beta, msgsb, n);

    update_mfma<<<(n + 63) / 64, 256, 0, stream>>>(xb, msgsb, wuT, upd_b, upd_g, upd_beta,
                                                   gate_w, gate_b, (float*)d_out, n);
}